// Round 3
// baseline (422.772 us; speedup 1.0000x reference)
//
#include <hip/hip_runtime.h>
#include <hip/hip_bf16.h>

#define BATCH 128
#define LQ    512
#define LK    512
#define DH    64
#define TQ    16
#define KC    128

// fp16 scores / bf16 attn overlay buffer, row stride in shorts.
// 520*2=1040 B keeps every row 16B-aligned (b128 A-frag reads legal).
// Bank audit: phase-2 b64 r/w = 4 words/bank balanced (0 extra cycles);
// phase-3 b128 A-frags = 8 words/bank balanced (0 extra). Only the 2-byte
// score scatter writes in phase 1 retain a small quad collision.
#define SSTR  520

typedef float    float4v __attribute__((ext_vector_type(4)));
typedef short    short8v __attribute__((ext_vector_type(8)));
typedef short    short4v __attribute__((ext_vector_type(4)));
typedef int      int4v   __attribute__((ext_vector_type(4)));
typedef _Float16 half4v  __attribute__((ext_vector_type(4)));

__device__ __forceinline__ short bf16r(float f) {
  union { float f; unsigned u; } x; x.f = f;
  unsigned r = x.u + 0x7FFFu + ((x.u >> 16) & 1u);
  return (short)(r >> 16);
}

// 6 blocks/CU (VGPR<=85): LDS 16.6KB would allow 8+, VGPR is the binding cap.
__global__ __launch_bounds__(256, 6)
void sdpa_kernel(const float* __restrict__ Q, const float* __restrict__ K,
                 const float* __restrict__ V, const int* __restrict__ KM,
                 const int* __restrict__ QM, float* __restrict__ OUT,
                 float* __restrict__ ATT)
{
  __shared__ short scs[TQ * SSTR];   // fp16 scores, then bf16 attn in place

  const int b    = blockIdx.x >> 5;
  const int q0   = (blockIdx.x & 31) * TQ;
  const int tid  = threadIdx.x;
  const int lane = tid & 63;
  const int wave = tid >> 6;
  const int lm   = lane & 15;
  const int quad = lane >> 4;

  // ---------------- Q A-fragments in registers ---------------------------
  const float* qrow = Q + ((size_t)(b * LQ + q0 + lm)) * DH + quad * 8;
  short8v aq0, aq1;
  {
    float4v f0 = *(const float4v*)(qrow + 0);
    float4v f1 = *(const float4v*)(qrow + 4);
    float4v f2 = *(const float4v*)(qrow + 32);
    float4v f3 = *(const float4v*)(qrow + 36);
#pragma unroll
    for (int e = 0; e < 4; ++e) {
      aq0[e]     = bf16r(f0[e]);
      aq0[e + 4] = bf16r(f1[e]);
      aq1[e]     = bf16r(f2[e]);
      aq1[e + 4] = bf16r(f3[e]);
    }
  }

  // ---------------- Phase 1: S = Q K^T (K B-frags direct from L2) --------
  // No LDS staging, no barriers inside the loop: compiler can software-
  // pipeline the K loads across kt iterations.
#pragma unroll
  for (int kt = 0; kt < LK / KC; ++kt) {
    const float* kbase = K + ((size_t)(b * LK + kt * KC)) * DH;
#pragma unroll
    for (int t = 0; t < 2; ++t) {
      int ntl = (wave * 2 + t) * 16;
      const float* kr = kbase + (ntl + lm) * DH + quad * 8;
      float4v f0 = *(const float4v*)(kr + 0);
      float4v f1 = *(const float4v*)(kr + 4);
      float4v f2 = *(const float4v*)(kr + 32);
      float4v f3 = *(const float4v*)(kr + 36);
      short8v b0, b1;
#pragma unroll
      for (int e = 0; e < 4; ++e) {
        b0[e]     = bf16r(f0[e]);
        b0[e + 4] = bf16r(f1[e]);
        b1[e]     = bf16r(f2[e]);
        b1[e + 4] = bf16r(f3[e]);
      }
      float4v acc = {0.f, 0.f, 0.f, 0.f};
      acc = __builtin_amdgcn_mfma_f32_16x16x32_bf16(aq0, b0, acc, 0, 0, 0);
      acc = __builtin_amdgcn_mfma_f32_16x16x32_bf16(aq1, b1, acc, 0, 0, 0);
      int n  = kt * KC + ntl + lm;
      int m0 = quad * 4;
#pragma unroll
      for (int j = 0; j < 4; ++j)
        *(_Float16*)&scs[(m0 + j) * SSTR + n] = (_Float16)acc[j];
    }
  }
  __syncthreads();                       // barrier 1 of 2: scores ready

  // ---------------- Phase 2: masks + softmax -----------------------------
  const int row = tid >> 4;
  const int col = tid & 15;
  const size_t gro = (size_t)(b * LQ + q0 + row) * LK;
  const int* kmr = KM + gro;
  const int* qmr = QM + gro;

  // Issue all 8 key-mask int4 loads back-to-back (MLP); 24 waves/CU of
  // occupancy covers the HBM miss latency.
  int4v kmv[8];
#pragma unroll
  for (int j = 0; j < 8; ++j)
    kmv[j] = *(const int4v*)(kmr + col * 4 + j * 64);

  float s[32];
  float mx = -INFINITY;
#pragma unroll
  for (int j = 0; j < 8; ++j) {
    half4v h4 = *(const half4v*)&scs[row * SSTR + col * 4 + j * 64];
#pragma unroll
    for (int e = 0; e < 4; ++e) {
      float val = kmv[j][e] ? -INFINITY : (float)h4[e];
      s[j * 4 + e] = val;
      mx = fmaxf(mx, val);
    }
  }
  // query-mask loads issued early: latency overlaps shuffles + exp
  int4v qmv[8];
#pragma unroll
  for (int j = 0; j < 8; ++j)
    qmv[j] = *(const int4v*)(qmr + col * 4 + j * 64);
#pragma unroll
  for (int off = 8; off; off >>= 1) mx = fmaxf(mx, __shfl_xor(mx, off, 64));
  float sum = 0.f;
#pragma unroll
  for (int j = 0; j < 32; ++j) {
    float p = __expf((s[j] - mx) * 0.125f);
    s[j] = p;
    sum += p;
  }
#pragma unroll
  for (int off = 8; off; off >>= 1) sum += __shfl_xor(sum, off, 64);
  const float inv = 1.f / sum;
  float* arow = ATT + gro;
#pragma unroll
  for (int j = 0; j < 8; ++j) {
    int kk = col * 4 + j * 64;
    float4v a4;
#pragma unroll
    for (int e = 0; e < 4; ++e)
      a4[e] = qmv[j][e] ? 0.f : s[j * 4 + e] * inv;
    *(float4v*)(arow + kk) = a4;               // fp32 attn out, coalesced
    short4v ab;
    ab[0] = bf16r(a4[0]); ab[1] = bf16r(a4[1]);
    ab[2] = bf16r(a4[2]); ab[3] = bf16r(a4[3]);
    *(short4v*)&scs[row * SSTR + kk] = ab;     // in-place bf16 overlay
  }
  __syncthreads();                       // barrier 2 of 2: attn ready

  // ---------------- Phase 3: O = A V (V B-frags direct from L2) ----------
  float4v oacc = {0.f, 0.f, 0.f, 0.f};
#pragma unroll
  for (int kt = 0; kt < LK / KC; ++kt) {
    // lane's V column for this wave's output d-range
    const float* vbase = V + ((size_t)(b * LK + kt * KC)) * DH + wave * 16 + lm;
#pragma unroll
    for (int ks = 0; ks < 4; ++ks) {
      const short* ap = &scs[lm * SSTR + kt * KC + ks * 32 + quad * 8];
      short8v a8 = *(const short8v*)ap;
      short8v b8;
#pragma unroll
      for (int j = 0; j < 8; ++j)
        b8[j] = bf16r(vbase[(size_t)(ks * 32 + quad * 8 + j) * DH]);
      oacc = __builtin_amdgcn_mfma_f32_16x16x32_bf16(a8, b8, oacc, 0, 0, 0);
    }
  }
  {
    int m0 = quad * 4;
    float* obase = OUT + ((size_t)(b * LQ + q0 + m0)) * DH + wave * 16 + lm;
    obase[0 * DH] = oacc[0];
    obase[1 * DH] = oacc[1];
    obase[2 * DH] = oacc[2];
    obase[3 * DH] = oacc[3];
  }
}

extern "C" void kernel_launch(void* const* d_in, const int* in_sizes, int n_in,
                              void* d_out, int out_size, void* d_ws, size_t ws_size,
                              hipStream_t stream) {
  const float* q  = (const float*)d_in[0];
  const float* k  = (const float*)d_in[1];
  const float* v  = (const float*)d_in[2];
  const int*   km = (const int*)d_in[3];
  const int*   qm = (const int*)d_in[4];
  float* out  = (float*)d_out;
  float* attn = out + (size_t)BATCH * LQ * DH;
  dim3 grid(BATCH * (LQ / TQ));
  dim3 block(256);
  hipLaunchKernelGGL(sdpa_kernel, grid, block, 0, stream,
                     q, k, v, km, qm, out, attn);
}

// Round 4
// 388.417 us; speedup vs baseline: 1.0884x; 1.0884x over previous
//
#include <hip/hip_runtime.h>
#include <hip/hip_bf16.h>

#define BATCH 128
#define LQ    512
#define LK    512
#define DH    64
#define TQ    16
#define KC    128

// scs: fp16 scores then bf16 attn overlay; SSTR=520 keeps rows 16B-aligned,
// phase-2 b64 r/w and phase-3 b128 A-frag reads bank-balanced (round-2 audit).
// vt: XOR-swizzled Vt[d][k-group], VROW=136 (round-2 measured: conflicts OK).
#define SSTR  520
#define VROW  136

typedef float    float4v __attribute__((ext_vector_type(4)));
typedef short    short8v __attribute__((ext_vector_type(8)));
typedef short    short4v __attribute__((ext_vector_type(4)));
typedef int      int4v   __attribute__((ext_vector_type(4)));
typedef _Float16 half4v  __attribute__((ext_vector_type(4)));

__device__ __forceinline__ short bf16r(float f) {
  union { float f; unsigned u; } x; x.f = f;
  unsigned r = x.u + 0x7FFFu + ((x.u >> 16) & 1u);
  return (short)(r >> 16);
}

__device__ __forceinline__ int4v ntload4(const int* p) {
  return __builtin_nontemporal_load((const int4v*)p);
}

// V chunk staging split into (global->reg) and (reg->LDS) halves so the
// global loads can overlap MFMA work, leaving only LDS stores between the
// two barriers of a buffer swap.
__device__ __forceinline__ void loadVchunk(const float* __restrict__ vsrc,
                                           int tid, float4v vr[8]) {
#pragma unroll
  for (int it = 0; it < 2; ++it) {
    int Bx = tid + 256 * it;
    int bR = Bx >> 4, bC = Bx & 15;          // k0 = 4*bR, d0 = 4*bC
    const float* vp = vsrc + bR * 4 * DH + bC * 4;
#pragma unroll
    for (int r = 0; r < 4; ++r)
      vr[it * 4 + r] = *(const float4v*)(vp + r * DH);
  }
}

__device__ __forceinline__ void storeVchunk(short* vt, int tid,
                                            const float4v vr[8]) {
#pragma unroll
  for (int it = 0; it < 2; ++it) {
    int Bx = tid + 256 * it;
    int bR = Bx >> 4, bC = Bx & 15;
#pragma unroll
    for (int e = 0; e < 4; ++e) {
      int d  = bC * 4 + e;
      int gp = bR ^ (d & 31);                // XOR swizzle
      short4v s4;
      s4[0] = bf16r(vr[it * 4 + 0][e]); s4[1] = bf16r(vr[it * 4 + 1][e]);
      s4[2] = bf16r(vr[it * 4 + 2][e]); s4[3] = bf16r(vr[it * 4 + 3][e]);
      *(short4v*)&vt[d * VROW + gp * 4] = s4;
    }
  }
}

__global__ __launch_bounds__(256, 4)
void sdpa_kernel(const float* __restrict__ Q, const float* __restrict__ K,
                 const float* __restrict__ V, const int* __restrict__ KM,
                 const int* __restrict__ QM, float* __restrict__ OUT,
                 float* __restrict__ ATT)
{
  __shared__ short scs[TQ * SSTR];   // 16.6 KB
  __shared__ short vt[DH * VROW];    // 17.4 KB  -> 34 KB total, 4 blocks/CU

  const int b    = blockIdx.x >> 5;
  const int q0   = (blockIdx.x & 31) * TQ;
  const int tid  = threadIdx.x;
  const int lane = tid & 63;
  const int wave = tid >> 6;
  const int lm   = lane & 15;
  const int quad = lane >> 4;

  const int row = tid >> 4;
  const int col = tid & 15;
  const size_t gro = (size_t)(b * LQ + q0 + row) * LK;

  // Key-mask prefetch: ~900-cyc HBM latency hides behind all of phase 1.
  int4v kmv[8];
#pragma unroll
  for (int j = 0; j < 8; ++j)
    kmv[j] = ntload4(KM + gro + col * 4 + j * 64);

  // ---------------- Q A-fragments in registers ---------------------------
  const float* qrow = Q + ((size_t)(b * LQ + q0 + lm)) * DH + quad * 8;
  short8v aq0, aq1;
  {
    float4v f0 = __builtin_nontemporal_load((const float4v*)(qrow + 0));
    float4v f1 = __builtin_nontemporal_load((const float4v*)(qrow + 4));
    float4v f2 = __builtin_nontemporal_load((const float4v*)(qrow + 32));
    float4v f3 = __builtin_nontemporal_load((const float4v*)(qrow + 36));
#pragma unroll
    for (int e = 0; e < 4; ++e) {
      aq0[e]     = bf16r(f0[e]);
      aq0[e + 4] = bf16r(f1[e]);
      aq1[e]     = bf16r(f2[e]);
      aq1[e + 4] = bf16r(f3[e]);
    }
  }

  // ---------------- Phase 1: S = Q K^T, K direct from L2 -----------------
  // 8 tiles (kt,t); explicit 1-deep pipeline: next tile's loads issue
  // before current tile's convert+MFMA, hiding L2 latency without LDS.
  {
    float4v c0, c1, c2, c3;
    {
      const float* kr = K + ((size_t)(b * LK + (wave * 2) * 16 + lm)) * DH + quad * 8;
      c0 = *(const float4v*)(kr + 0);  c1 = *(const float4v*)(kr + 4);
      c2 = *(const float4v*)(kr + 32); c3 = *(const float4v*)(kr + 36);
    }
#pragma unroll
    for (int p = 0; p < 8; ++p) {
      float4v n0, n1, n2, n3;
      if (p < 7) {
        int np = p + 1, kt = np >> 1, t = np & 1;
        const float* kr = K + ((size_t)(b * LK + kt * KC + (wave * 2 + t) * 16 + lm)) * DH + quad * 8;
        n0 = *(const float4v*)(kr + 0);  n1 = *(const float4v*)(kr + 4);
        n2 = *(const float4v*)(kr + 32); n3 = *(const float4v*)(kr + 36);
      }
      short8v b0, b1;
#pragma unroll
      for (int e = 0; e < 4; ++e) {
        b0[e]     = bf16r(c0[e]);
        b0[e + 4] = bf16r(c1[e]);
        b1[e]     = bf16r(c2[e]);
        b1[e + 4] = bf16r(c3[e]);
      }
      float4v acc = {0.f, 0.f, 0.f, 0.f};
      acc = __builtin_amdgcn_mfma_f32_16x16x32_bf16(aq0, b0, acc, 0, 0, 0);
      acc = __builtin_amdgcn_mfma_f32_16x16x32_bf16(aq1, b1, acc, 0, 0, 0);
      int kt = p >> 1, t = p & 1;
      int n  = kt * KC + (wave * 2 + t) * 16 + lm;
      int m0 = quad * 4;
#pragma unroll
      for (int j = 0; j < 4; ++j)
        *(_Float16*)&scs[(m0 + j) * SSTR + n] = (_Float16)acc[j];
      if (p < 7) { c0 = n0; c1 = n1; c2 = n2; c3 = n3; }
    }
  }
  __syncthreads();                       // scores ready

  // ---------------- Phase 2: masks + softmax -----------------------------
  float s[32];
  float mx = -INFINITY;
#pragma unroll
  for (int j = 0; j < 8; ++j) {
    half4v h4 = *(const half4v*)&scs[row * SSTR + col * 4 + j * 64];
#pragma unroll
    for (int e = 0; e < 4; ++e) {
      float val = kmv[j][e] ? -INFINITY : (float)h4[e];
      s[j * 4 + e] = val;
      mx = fmaxf(mx, val);
    }
  }
  // query-mask loads + V(kt=0) chunk loads: latency overlaps shuffles + exp
  int4v qmv[8];
#pragma unroll
  for (int j = 0; j < 8; ++j)
    qmv[j] = ntload4(QM + gro + col * 4 + j * 64);
  float4v vr[8];
  loadVchunk(V + ((size_t)(b * LK)) * DH, tid, vr);

#pragma unroll
  for (int off = 8; off; off >>= 1) mx = fmaxf(mx, __shfl_xor(mx, off, 64));
  float sum = 0.f;
#pragma unroll
  for (int j = 0; j < 32; ++j) {
    float p = __expf((s[j] - mx) * 0.125f);
    s[j] = p;
    sum += p;
  }
#pragma unroll
  for (int off = 8; off; off >>= 1) sum += __shfl_xor(sum, off, 64);
  const float inv = 1.f / sum;
  float* arow = ATT + gro;
#pragma unroll
  for (int j = 0; j < 8; ++j) {
    int kk = col * 4 + j * 64;
    float4v a4;
#pragma unroll
    for (int e = 0; e < 4; ++e)
      a4[e] = qmv[j][e] ? 0.f : s[j * 4 + e] * inv;
    __builtin_nontemporal_store(a4, (float4v*)(arow + kk));  // fp32 attn out
    short4v ab;
    ab[0] = bf16r(a4[0]); ab[1] = bf16r(a4[1]);
    ab[2] = bf16r(a4[2]); ab[3] = bf16r(a4[3]);
    *(short4v*)&scs[row * SSTR + kk] = ab;     // in-place bf16 overlay
  }
  storeVchunk(vt, tid, vr);              // V(0) staging, ordered by barrier
  __syncthreads();                       // attn + Vt(0) ready

  // ---------------- Phase 3: O = A V -------------------------------------
  float4v oacc = {0.f, 0.f, 0.f, 0.f};
#pragma unroll
  for (int kt = 0; kt < 4; ++kt) {
    if (kt < 3)                          // prefetch next chunk under MFMA
      loadVchunk(V + ((size_t)(b * LK + (kt + 1) * KC)) * DH, tid, vr);
#pragma unroll
    for (int ks = 0; ks < 4; ++ks) {
      const short* ap = &scs[lm * SSTR + kt * KC + ks * 32 + quad * 8];
      short8v a8 = *(const short8v*)ap;
      int n  = wave * 16 + lm;
      int g0 = ks * 8 + quad * 2;
      short4v lo = *(const short4v*)&vt[n * VROW + ((g0    ) ^ (n & 31)) * 4];
      short4v hi = *(const short4v*)&vt[n * VROW + ((g0 + 1) ^ (n & 31)) * 4];
      short8v b8;
      b8[0] = lo[0]; b8[1] = lo[1]; b8[2] = lo[2]; b8[3] = lo[3];
      b8[4] = hi[0]; b8[5] = hi[1]; b8[6] = hi[2]; b8[7] = hi[3];
      oacc = __builtin_amdgcn_mfma_f32_16x16x32_bf16(a8, b8, oacc, 0, 0, 0);
    }
    if (kt < 3) {
      __syncthreads();                   // all waves done reading vt
      storeVchunk(vt, tid, vr);          // only LDS stores between barriers
      __syncthreads();                   // vt(kt+1) ready
    }
  }
  {
    int m0 = quad * 4;
    float* obase = OUT + ((size_t)(b * LQ + q0 + m0)) * DH + wave * 16 + lm;
#pragma unroll
    for (int j = 0; j < 4; ++j)
      __builtin_nontemporal_store(oacc[j], obase + j * DH);
  }
}

extern "C" void kernel_launch(void* const* d_in, const int* in_sizes, int n_in,
                              void* d_out, int out_size, void* d_ws, size_t ws_size,
                              hipStream_t stream) {
  const float* q  = (const float*)d_in[0];
  const float* k  = (const float*)d_in[1];
  const float* v  = (const float*)d_in[2];
  const int*   km = (const int*)d_in[3];
  const int*   qm = (const int*)d_in[4];
  float* out  = (float*)d_out;
  float* attn = out + (size_t)BATCH * LQ * DH;
  dim3 grid(BATCH * (LQ / TQ));
  dim3 block(256);
  hipLaunchKernelGGL(sdpa_kernel, grid, block, 0, stream,
                     q, k, v, km, qm, out, attn);
}